// Round 6
// baseline (654.837 us; speedup 1.0000x reference)
//
#include <hip/hip_runtime.h>

// ---------------------------------------------------------------------------
// out[n] = sum_f ( z_nf^T W_f z_nf - log(clip(det(W_f S1_f + I),1e-5,1e5)) )
//          + log(n1/n2)
// N=4096, K=256, P2=96
//
// R9: det wave runs at s_setprio(2):
//  - R8 counters showed fused = short quad phase (~60-80 us, high occupancy,
//    HBM-served) + long ~1-wave/CU det tail stretched 105 -> 252 us. det's
//    serial dependent chain loses SIMD issue arbitration to 8+ always-ready
//    quad waves at every hop.
//  - s_setprio(2) on the det wave biases issue arbitration toward the
//    critical-path wave; quad (prio 0) loses a negligible slot fraction.
//  - everything else byte-identical to R8.
// finalize unchanged.
// ---------------------------------------------------------------------------

typedef __attribute__((ext_vector_type(8))) short bf16x8;
typedef __attribute__((ext_vector_type(4))) float f32x4;

#define WFENCE() asm volatile("" ::: "memory")

__device__ __forceinline__ unsigned short f2bf(float x) {
  unsigned int u = __builtin_bit_cast(unsigned int, x);
  u += 0x7fffu + ((u >> 16) & 1u);   // round-to-nearest-even
  return (unsigned short)(u >> 16);
}
__device__ __forceinline__ float bf2f(unsigned short h) {
  unsigned int u = ((unsigned int)h) << 16;
  return __builtin_bit_cast(float, u);
}

#define ALD 100   // Al row stride (dwords)
#define WLD 35    // Wc row stride
#define ZLD 104

// ---------------------------------------------------------------------------
// det body: one wave, barrier-free (single-wave LDS is in-order).
// smem overlay: Wc[0..3360) Sc[3360..6560) during GEMM; Al[0..9600) after.
// ---------------------------------------------------------------------------
__device__ __forceinline__ void det_body(const int lane, const int f,
                                         const float* __restrict__ W,
                                         const float* __restrict__ S1,
                                         float* __restrict__ logdet,
                                         float* smem) {
  float* Wc = smem;          // 96*35 = 3,360 floats (GEMM phase only)
  float* Sc = smem + 3360;   // 32*100 = 3,200 floats (GEMM phase only)
  float* Al = smem;          // 96*100 = 9,600 floats (written after GEMM)

  const float* Wg = W + (size_t)f * 9216;
  const float* Sg = S1 + (size_t)f * 9216;

  const int i0 = (lane >> 3) * 12;
  const int j0 = (lane & 7) * 12;

  float acc[12][12];
#pragma unroll
  for (int a = 0; a < 12; ++a)
#pragma unroll
    for (int b = 0; b < 12; ++b) acc[a][b] = 0.f;

  for (int kc = 0; kc < 3; ++kc) {
#pragma unroll
    for (int it = 0; it < 12; ++it) {
      int c = lane + it * 64;          // 0..767
      int i = c >> 3;
      int k4 = (c & 7) << 2;
      const float4 v =
          *reinterpret_cast<const float4*>(Wg + i * 96 + kc * 32 + k4);
      Wc[i * WLD + k4 + 0] = v.x;
      Wc[i * WLD + k4 + 1] = v.y;
      Wc[i * WLD + k4 + 2] = v.z;
      Wc[i * WLD + k4 + 3] = v.w;
    }
#pragma unroll
    for (int it = 0; it < 12; ++it) {
      int c = lane + it * 64;
      int kk = c / 24;
      int j4 = (c % 24) << 2;
      const float4 v =
          *reinterpret_cast<const float4*>(Sg + (kc * 32 + kk) * 96 + j4);
      *reinterpret_cast<float4*>(&Sc[kk * 100 + j4]) = v;
    }
    WFENCE();
#pragma unroll 2
    for (int kk = 0; kk < 32; ++kk) {
      float wv[12];
#pragma unroll
      for (int r = 0; r < 12; ++r) wv[r] = Wc[(i0 + r) * WLD + kk];
      float sv[12];
      const float4 s0 = *reinterpret_cast<const float4*>(&Sc[kk * 100 + j0]);
      const float4 s1 =
          *reinterpret_cast<const float4*>(&Sc[kk * 100 + j0 + 4]);
      const float4 s2 =
          *reinterpret_cast<const float4*>(&Sc[kk * 100 + j0 + 8]);
      sv[0] = s0.x; sv[1] = s0.y; sv[2] = s0.z; sv[3] = s0.w;
      sv[4] = s1.x; sv[5] = s1.y; sv[6] = s1.z; sv[7] = s1.w;
      sv[8] = s2.x; sv[9] = s2.y; sv[10] = s2.z; sv[11] = s2.w;
#pragma unroll
      for (int a = 0; a < 12; ++a)
#pragma unroll
        for (int b = 0; b < 12; ++b) acc[a][b] += wv[a] * sv[b];
    }
    WFENCE();
  }

  // Al = acc + I  (overwrites Wc/Sc region -- all GEMM reads already done,
  // single-wave DS pipe is in-order)
#pragma unroll
  for (int a = 0; a < 12; ++a) {
    int i = i0 + a;
#pragma unroll
    for (int c4 = 0; c4 < 3; ++c4) {
      float4 v;
      v.x = acc[a][c4 * 4 + 0] + ((i == j0 + c4 * 4 + 0) ? 1.f : 0.f);
      v.y = acc[a][c4 * 4 + 1] + ((i == j0 + c4 * 4 + 1) ? 1.f : 0.f);
      v.z = acc[a][c4 * 4 + 2] + ((i == j0 + c4 * 4 + 2) ? 1.f : 0.f);
      v.w = acc[a][c4 * 4 + 3] + ((i == j0 + c4 * 4 + 3) ? 1.f : 0.f);
      *reinterpret_cast<float4*>(&Al[i * ALD + j0 + c4 * 4]) = v;
    }
  }
  WFENCE();

  // ======================= blocked LU, NB = 8 ==============================
  float ls = 0.f;
  int neg = 0;
  int sgn = 0;

  for (int p = 0; p < 12; ++p) {
    const int c0 = p * 8;
    const int NC = 88 - c0;
    const int NT = NC >> 2;
    const bool e0 = lane <= 95 - c0;
    const bool e1 = (c0 < 32) && (lane <= 31 - c0);

    float P0[8], P1[8];
#pragma unroll
    for (int m = 0; m < 8; ++m) { P0[m] = 0.f; P1[m] = 0.f; }
    if (e0) {
      const float4 x =
          *reinterpret_cast<const float4*>(&Al[(c0 + lane) * ALD + c0]);
      const float4 y =
          *reinterpret_cast<const float4*>(&Al[(c0 + lane) * ALD + c0 + 4]);
      P0[0] = x.x; P0[1] = x.y; P0[2] = x.z; P0[3] = x.w;
      P0[4] = y.x; P0[5] = y.y; P0[6] = y.z; P0[7] = y.w;
    }
    if (e1) {
      const float4 x =
          *reinterpret_cast<const float4*>(&Al[(c0 + 64 + lane) * ALD + c0]);
      const float4 y =
          *reinterpret_cast<const float4*>(&Al[(c0 + 64 + lane) * ALD + c0 + 4]);
      P1[0] = x.x; P1[1] = x.y; P1[2] = x.z; P1[3] = x.w;
      P1[4] = y.x; P1[5] = y.y; P1[6] = y.z; P1[7] = y.w;
    }

#pragma unroll
    for (int j = 0; j < 8; ++j) {
      const int jc = c0 + j;
      float pv;
      int tried = 0;
      for (;;) {
        pv = __shfl(P0[j], j);
        if (fabsf(pv) >= 1e-3f || tried) break;
        tried = 1;
        unsigned k0 = (e0 && lane >= j)
                          ? ((__float_as_uint(fabsf(P0[j])) & ~127u) |
                             (unsigned)lane)
                          : 0u;
        unsigned k1 = e1 ? ((__float_as_uint(fabsf(P1[j])) & ~127u) | 64u |
                            (unsigned)lane)
                         : 0u;
        unsigned key = k0 > k1 ? k0 : k1;
#pragma unroll
        for (int m = 1; m < 64; m <<= 1) {
          unsigned o = (unsigned)__shfl_xor((int)key, m);
          key = key > o ? key : o;
        }
        const int wl = (int)(key & 63u);
        const int slot = (int)((key >> 6) & 1u);
        const int bi = c0 + slot * 64 + wl;
        if (bi <= jc) break;
        sgn ^= 1;
#pragma unroll
        for (int m = 0; m < 8; ++m) {
          const float vj = __shfl(P0[m], j);
          const float vb0 = __shfl(P0[m], wl);
          const float vb1 = __shfl(P1[m], wl);
          const float vb = slot ? vb1 : vb0;
          if (lane == j) P0[m] = vb;
          if (lane == wl) {
            if (slot) P1[m] = vj;
            else P0[m] = vj;
          }
        }
        if (lane < NT) {
          const int col0 = c0 + 8 + lane * 4;
          float4 xx = *reinterpret_cast<float4*>(&Al[jc * ALD + col0]);
          float4 yy = *reinterpret_cast<float4*>(&Al[bi * ALD + col0]);
          *reinterpret_cast<float4*>(&Al[jc * ALD + col0]) = yy;
          *reinterpret_cast<float4*>(&Al[bi * ALD + col0]) = xx;
        }
        WFENCE();
      }
      const float rpv = __builtin_amdgcn_rcpf(pv);
      const bool up0 = e0 && (lane > j);
      const float L0 = P0[j] * rpv;
      const float L1 = P1[j] * rpv;
      if (up0) P0[j] = L0;
      if (e1) P1[j] = L1;
#pragma unroll
      for (int jj = j + 1; jj < 8; ++jj) {
        const float u = __shfl(P0[jj], j);
        if (up0) P0[jj] -= L0 * u;
        if (e1) P1[jj] -= L1 * u;
      }
      ls += logf(fabsf(pv));
      if (pv < 0.f) neg ^= 1;
    }
    WFENCE();

    if (NC > 0) {
      // U12 solve
      const int ca = c0 + 8 + lane;
      const bool va = lane < NC;
      const int cb = ca + 64;
      const bool vb = (lane + 64) < NC;
      float a[8], b[8];
#pragma unroll
      for (int i = 0; i < 8; ++i) {
        a[i] = va ? Al[(c0 + i) * ALD + ca] : 0.f;
        b[i] = vb ? Al[(c0 + i) * ALD + cb] : 0.f;
      }
#pragma unroll
      for (int jj = 1; jj < 8; ++jj)
#pragma unroll
        for (int i = 0; i < jj; ++i) {
          const float Lv = __shfl(P0[i], jj);
          a[jj] -= Lv * a[i];
          b[jj] -= Lv * b[i];
        }
#pragma unroll
      for (int i = 0; i < 8; ++i) {
        if (va) Al[(c0 + i) * ALD + ca] = a[i];
        if (vb) Al[(c0 + i) * ALD + cb] = b[i];
      }
      WFENCE();

      // trailing rank-8 update
      const bool r0v = e0 && (lane >= 8);
      const bool r1v = e1;
      const int r0 = (c0 + lane) * ALD;
      const int r1 = (c0 + 64 + lane) * ALD;
      for (int ct = 0; ct < NT; ++ct) {
        const int col0 = c0 + 8 + ct * 4;
        float4 u[8];
#pragma unroll
        for (int i = 0; i < 8; ++i)
          u[i] = *reinterpret_cast<const float4*>(&Al[(c0 + i) * ALD + col0]);
        if (r0v) {
          float4 x = *reinterpret_cast<float4*>(&Al[r0 + col0]);
#pragma unroll
          for (int i = 0; i < 8; ++i) {
            x.x -= P0[i] * u[i].x;
            x.y -= P0[i] * u[i].y;
            x.z -= P0[i] * u[i].z;
            x.w -= P0[i] * u[i].w;
          }
          *reinterpret_cast<float4*>(&Al[r0 + col0]) = x;
        }
        if (r1v) {
          float4 x = *reinterpret_cast<float4*>(&Al[r1 + col0]);
#pragma unroll
          for (int i = 0; i < 8; ++i) {
            x.x -= P1[i] * u[i].x;
            x.y -= P1[i] * u[i].y;
            x.z -= P1[i] * u[i].z;
            x.w -= P1[i] * u[i].w;
          }
          *reinterpret_cast<float4*>(&Al[r1 + col0]) = x;
        }
      }
    }
    WFENCE();
  }

  if (lane == 0) {
    const float LMIN = -11.5129254f, LMAX = 11.5129254f;  // log(1e-5), log(1e5)
    float c;
    if (neg ^ sgn) c = LMIN;
    else c = fminf(fmaxf(ls, LMIN), LMAX);
    logdet[f] = c;
  }
}

// ---------------------------------------------------------------------------
// quad body (identical math to R8).
// ---------------------------------------------------------------------------
__device__ __forceinline__ void quad_body(const int tid, const int idx,
                                          const float* __restrict__ z,
                                          const float* __restrict__ W,
                                          float* __restrict__ partial,
                                          float* smem) {
  unsigned short* Zb = reinterpret_cast<unsigned short*>(smem);
  unsigned short* Wb = Zb + 128 * ZLD;   // 13,312 shorts in

  const int lane = tid & 63, wave = tid >> 6;
  const int n0 = (idx & 31) * 128;
  const int f0 = (idx >> 5) * 16;
  const int lrow = lane & 15;
  const int lq = lane >> 4;
  const int lk8 = lq * 8;
  const int rgrp = tid >> 3;
  const int cgrp = tid & 7;

  float dotacc[2][4];
#pragma unroll
  for (int mt = 0; mt < 2; ++mt)
#pragma unroll
    for (int i = 0; i < 4; ++i) dotacc[mt][i] = 0.f;

  for (int ff = 0; ff < 16; ++ff) {
    const int f = f0 + ff;
#pragma unroll
    for (int p = 0; p < 4; ++p) {
      int r = p * 32 + rgrp;
      const float4* src = reinterpret_cast<const float4*>(
          z + (size_t)(n0 + r) * 24576 + (size_t)f * 96);
#pragma unroll
      for (int cc = 0; cc < 3; ++cc) {
        int c = cgrp + cc * 8;
        float4 d = src[c];
        ushort4 s;
        s.x = f2bf(d.x); s.y = f2bf(d.y); s.z = f2bf(d.z); s.w = f2bf(d.w);
        *reinterpret_cast<ushort4*>(&Zb[r * ZLD + c * 4]) = s;
      }
    }
    const float4* wsrc =
        reinterpret_cast<const float4*>(W + (size_t)f * 9216);
#pragma unroll
    for (int it = 0; it < 9; ++it) {
      int c = tid + it * 256;
      int k = c / 24, q4 = (c % 24) << 2;
      float4 d = wsrc[c];
      ushort4 s;
      s.x = f2bf(d.x); s.y = f2bf(d.y); s.z = f2bf(d.z); s.w = f2bf(d.w);
      *reinterpret_cast<ushort4*>(&Wb[k * ZLD + q4]) = s;
    }
    __syncthreads();

    f32x4 acc[2][6];
#pragma unroll
    for (int mt = 0; mt < 2; ++mt)
#pragma unroll
      for (int nt = 0; nt < 6; ++nt) acc[mt][nt] = (f32x4){0.f, 0.f, 0.f, 0.f};

#pragma unroll
    for (int ks = 0; ks < 3; ++ks) {
      bf16x8 a0 = *reinterpret_cast<const bf16x8*>(
          &Zb[(wave * 32 + lrow) * ZLD + ks * 32 + lk8]);
      bf16x8 a1 = *reinterpret_cast<const bf16x8*>(
          &Zb[(wave * 32 + 16 + lrow) * ZLD + ks * 32 + lk8]);
#pragma unroll
      for (int nt = 0; nt < 6; ++nt) {
        bf16x8 b = *reinterpret_cast<const bf16x8*>(
            &Wb[(nt * 16 + lrow) * ZLD + ks * 32 + lk8]);
        acc[0][nt] =
            __builtin_amdgcn_mfma_f32_16x16x32_bf16(a0, b, acc[0][nt], 0, 0, 0);
        acc[1][nt] =
            __builtin_amdgcn_mfma_f32_16x16x32_bf16(a1, b, acc[1][nt], 0, 0, 0);
      }
    }

#pragma unroll
    for (int mt = 0; mt < 2; ++mt) {
      int rbase = wave * 32 + mt * 16 + lq * 4;
#pragma unroll
      for (int i = 0; i < 4; ++i) {
        int row = rbase + i;
        float s = 0.f;
#pragma unroll
        for (int nt = 0; nt < 6; ++nt) {
          float zv = bf2f(Zb[row * ZLD + nt * 16 + lrow]);
          s += acc[mt][nt][i] * zv;
        }
        dotacc[mt][i] += s;
      }
    }
    __syncthreads();
  }

#pragma unroll
  for (int mt = 0; mt < 2; ++mt)
#pragma unroll
    for (int i = 0; i < 4; ++i) {
      float v = dotacc[mt][i];
      v += __shfl_xor(v, 1);
      v += __shfl_xor(v, 2);
      v += __shfl_xor(v, 4);
      v += __shfl_xor(v, 8);
      dotacc[mt][i] = v;
    }
  if (lrow == 0) {
#pragma unroll
    for (int mt = 0; mt < 2; ++mt) {
      int row = wave * 32 + mt * 16 + lq * 4;
      float4 o = {dotacc[mt][0], dotacc[mt][1], dotacc[mt][2], dotacc[mt][3]};
      *reinterpret_cast<float4*>(
          &partial[(size_t)(idx >> 5) * 4096 + n0 + row]) = o;
    }
  }
}

// ---------------------------------------------------------------------------
// Fused kernel: blocks 0..255 det (priority-2 wave), 256..767 quad.
// LDS = 46,592 B union -> 3 blocks/CU, 768 blocks = full residency.
// ---------------------------------------------------------------------------
__global__ __launch_bounds__(256) void fused_kernel(
    const float* __restrict__ z, const float* __restrict__ W,
    const float* __restrict__ S1, float* __restrict__ partial,
    float* __restrict__ logdet) {
  __shared__ alignas(16) float smem[11648];   // 46,592 B union
  if (blockIdx.x < 256) {
    if (threadIdx.x >= 64) return;            // det is single-wave
    __builtin_amdgcn_s_setprio(2);            // critical-path wave wins issue
    det_body(threadIdx.x, blockIdx.x, W, S1, logdet, smem);
  } else {
    quad_body(threadIdx.x, blockIdx.x - 256, z, W, partial, smem);
  }
}

// ---------------------------------------------------------------------------
// finalize: out[n] = sum_ft partial[ft][n] - sum_f logdet[f] + log(n1/n2)
// ---------------------------------------------------------------------------
__global__ __launch_bounds__(256) void finalize_kernel(
    const float* __restrict__ partial, const float* __restrict__ logdet,
    const int* __restrict__ n1p, const int* __restrict__ n2p,
    float* __restrict__ out) {
  __shared__ float red[256];
  const int t = threadIdx.x;
  red[t] = logdet[t];
  __syncthreads();
  for (int s = 128; s > 0; s >>= 1) {
    if (t < s) red[t] += red[t + s];
    __syncthreads();
  }
  const float S = red[0];
  const int n = blockIdx.x * 256 + t;
  float acc = 0.f;
#pragma unroll
  for (int ft = 0; ft < 16; ++ft) acc += partial[ft * 4096 + n];
  const float cst = logf((float)(*n1p) / (float)(*n2p));
  out[n] = acc - S + cst;
}

// ---------------------------------------------------------------------------
extern "C" void kernel_launch(void* const* d_in, const int* in_sizes, int n_in,
                              void* d_out, int out_size, void* d_ws,
                              size_t ws_size, hipStream_t stream) {
  const float* z  = (const float*)d_in[0];
  const float* s1 = (const float*)d_in[1];
  // d_in[2] = sigma_2 (unused by the reference)
  const float* w  = (const float*)d_in[3];
  const int* n1   = (const int*)d_in[4];
  const int* n2   = (const int*)d_in[5];
  float* out      = (float*)d_out;

  char* ws = (char*)d_ws;
  float* partial = (float*)ws;                 // 16*4096*4 = 262,144 B
  float* logdet  = (float*)(ws + 262144);      // 256*4     =   1,024 B

  fused_kernel<<<dim3(768), dim3(256), 0, stream>>>(z, w, s1, partial, logdet);
  finalize_kernel<<<dim3(16), dim3(256), 0, stream>>>(partial, logdet, n1, n2,
                                                      out);
}

// Round 7
// 633.964 us; speedup vs baseline: 1.0329x; 1.0329x over previous
//
#include <hip/hip_runtime.h>

// ---------------------------------------------------------------------------
// out[n] = sum_f ( z_nf^T W_f z_nf - log(clip(det(W_f S1_f + I),1e-5,1e5)) )
//          + log(n1/n2)
// N=4096, K=256, P2=96
//
// R10: VGPR was the fusion blocker. 152 VGPR rounds to the 256-reg quantum
// -> 8 waves/CU -> a det wave + an 8-wave quad block never co-schedule;
// R7-R9 ran det and quad SERIALLY inside one dispatch (252us invariant).
//  - quad: nt split into 2 groups of 3 (acc 48->24 live regs), per-group
//    epilogue; same per-element math order.
//  - det: 4-wave. GEMM per-thread 3x12 tile (acc 36 regs, was 144);
//    panel fact register-resident in wave 0 + L/U writeback; U12 solve
//    col-per-thread; trailing update row-per-thread.
//  - __launch_bounds__(256,4) pins <=128 VGPR -> 16 waves/CU ->
//    det(4w)+quad(8w) co-resident; 2 quad blocks/CU after det drains.
// finalize unchanged.
// ---------------------------------------------------------------------------

typedef __attribute__((ext_vector_type(8))) short bf16x8;
typedef __attribute__((ext_vector_type(4))) float f32x4;

#define WFENCE() asm volatile("" ::: "memory")

__device__ __forceinline__ unsigned short f2bf(float x) {
  unsigned int u = __builtin_bit_cast(unsigned int, x);
  u += 0x7fffu + ((u >> 16) & 1u);   // round-to-nearest-even
  return (unsigned short)(u >> 16);
}
__device__ __forceinline__ float bf2f(unsigned short h) {
  unsigned int u = ((unsigned int)h) << 16;
  return __builtin_bit_cast(float, u);
}

#define ALD 100   // Al row stride (dwords)
#define WLD 35    // Wc row stride
#define ZLD 104

// ---------------------------------------------------------------------------
// det body: 4 waves. smem overlay: Wc[0..3360) Sc[3360..6560) during GEMM;
// Al[0..9600) after. Panel fact is wave-0 register-resident; solve/trailing
// are thread-parallel.
// ---------------------------------------------------------------------------
__device__ __forceinline__ void det_body(const int tid, const int f,
                                         const float* __restrict__ W,
                                         const float* __restrict__ S1,
                                         float* __restrict__ logdet,
                                         float* smem) {
  float* Wc = smem;          // 96*35 floats (GEMM phase only)
  float* Sc = smem + 3360;   // 32*100 floats (GEMM phase only)
  float* Al = smem;          // 96*100 floats (after GEMM)

  const int lane = tid & 63;
  const float* Wg = W + (size_t)f * 9216;
  const float* Sg = S1 + (size_t)f * 9216;

  // ---- GEMM: A = W @ S1, per-thread 3x12 tile (256 threads) ----
  const int i0 = (tid >> 3) * 3;    // 32 row-groups x 3
  const int j0 = (tid & 7) * 12;    // 8 col-groups x 12

  float acc[3][12];
#pragma unroll
  for (int a = 0; a < 3; ++a)
#pragma unroll
    for (int b = 0; b < 12; ++b) acc[a][b] = 0.f;

  for (int kc = 0; kc < 3; ++kc) {
#pragma unroll
    for (int it = 0; it < 3; ++it) {
      int c = tid + it * 256;          // 0..767
      int i = c >> 3;
      int k4 = (c & 7) << 2;
      const float4 v =
          *reinterpret_cast<const float4*>(Wg + i * 96 + kc * 32 + k4);
      Wc[i * WLD + k4 + 0] = v.x;
      Wc[i * WLD + k4 + 1] = v.y;
      Wc[i * WLD + k4 + 2] = v.z;
      Wc[i * WLD + k4 + 3] = v.w;
    }
#pragma unroll
    for (int it = 0; it < 3; ++it) {
      int c = tid + it * 256;
      int kk = c / 24;
      int j4 = (c % 24) << 2;
      const float4 v =
          *reinterpret_cast<const float4*>(Sg + (kc * 32 + kk) * 96 + j4);
      *reinterpret_cast<float4*>(&Sc[kk * 100 + j4]) = v;
    }
    __syncthreads();
#pragma unroll 2
    for (int kk = 0; kk < 32; ++kk) {
      float wv[3];
#pragma unroll
      for (int r = 0; r < 3; ++r) wv[r] = Wc[(i0 + r) * WLD + kk];
      float sv[12];
      const float4 s0 = *reinterpret_cast<const float4*>(&Sc[kk * 100 + j0]);
      const float4 s1 =
          *reinterpret_cast<const float4*>(&Sc[kk * 100 + j0 + 4]);
      const float4 s2 =
          *reinterpret_cast<const float4*>(&Sc[kk * 100 + j0 + 8]);
      sv[0] = s0.x; sv[1] = s0.y; sv[2] = s0.z; sv[3] = s0.w;
      sv[4] = s1.x; sv[5] = s1.y; sv[6] = s1.z; sv[7] = s1.w;
      sv[8] = s2.x; sv[9] = s2.y; sv[10] = s2.z; sv[11] = s2.w;
#pragma unroll
      for (int a = 0; a < 3; ++a)
#pragma unroll
        for (int b = 0; b < 12; ++b) acc[a][b] += wv[a] * sv[b];
    }
    __syncthreads();
  }

  // Al = acc + I (overwrites Wc/Sc; all GEMM reads done by the barrier)
#pragma unroll
  for (int a = 0; a < 3; ++a) {
    int i = i0 + a;
#pragma unroll
    for (int c4 = 0; c4 < 3; ++c4) {
      float4 v;
      v.x = acc[a][c4 * 4 + 0] + ((i == j0 + c4 * 4 + 0) ? 1.f : 0.f);
      v.y = acc[a][c4 * 4 + 1] + ((i == j0 + c4 * 4 + 1) ? 1.f : 0.f);
      v.z = acc[a][c4 * 4 + 2] + ((i == j0 + c4 * 4 + 2) ? 1.f : 0.f);
      v.w = acc[a][c4 * 4 + 3] + ((i == j0 + c4 * 4 + 3) ? 1.f : 0.f);
      *reinterpret_cast<float4*>(&Al[i * ALD + j0 + c4 * 4]) = v;
    }
  }
  __syncthreads();

  // ======================= blocked LU, NB = 8 ==============================
  float ls = 0.f;    // valid in wave 0 (uniform there)
  int neg = 0;
  int sgn = 0;

  for (int p = 0; p < 12; ++p) {
    const int c0 = p * 8;
    const int NC = 88 - c0;            // trailing cols == trailing rows
    const int NT = NC >> 2;

    if (tid < 64) {
      // ---- wave-0 panel factorization, register-resident ----
      const bool e0 = lane <= 95 - c0;
      const bool e1 = (c0 < 32) && (lane <= 31 - c0);
      float P0[8], P1[8];
#pragma unroll
      for (int m = 0; m < 8; ++m) { P0[m] = 0.f; P1[m] = 0.f; }
      if (e0) {
        const float4 x =
            *reinterpret_cast<const float4*>(&Al[(c0 + lane) * ALD + c0]);
        const float4 y =
            *reinterpret_cast<const float4*>(&Al[(c0 + lane) * ALD + c0 + 4]);
        P0[0] = x.x; P0[1] = x.y; P0[2] = x.z; P0[3] = x.w;
        P0[4] = y.x; P0[5] = y.y; P0[6] = y.z; P0[7] = y.w;
      }
      if (e1) {
        const float4 x = *reinterpret_cast<const float4*>(
            &Al[(c0 + 64 + lane) * ALD + c0]);
        const float4 y = *reinterpret_cast<const float4*>(
            &Al[(c0 + 64 + lane) * ALD + c0 + 4]);
        P1[0] = x.x; P1[1] = x.y; P1[2] = x.z; P1[3] = x.w;
        P1[4] = y.x; P1[5] = y.y; P1[6] = y.z; P1[7] = y.w;
      }

#pragma unroll
      for (int j = 0; j < 8; ++j) {
        const int jc = c0 + j;
        float pv;
        int tried = 0;
        for (;;) {
          pv = __shfl(P0[j], j);
          if (fabsf(pv) >= 1e-3f || tried) break;
          tried = 1;
          unsigned k0 = (e0 && lane >= j)
                            ? ((__float_as_uint(fabsf(P0[j])) & ~127u) |
                               (unsigned)lane)
                            : 0u;
          unsigned k1 = e1 ? ((__float_as_uint(fabsf(P1[j])) & ~127u) | 64u |
                              (unsigned)lane)
                           : 0u;
          unsigned key = k0 > k1 ? k0 : k1;
#pragma unroll
          for (int m = 1; m < 64; m <<= 1) {
            unsigned o = (unsigned)__shfl_xor((int)key, m);
            key = key > o ? key : o;
          }
          const int wl = (int)(key & 63u);
          const int slot = (int)((key >> 6) & 1u);
          const int bi = c0 + slot * 64 + wl;
          if (bi <= jc) break;
          sgn ^= 1;
#pragma unroll
          for (int m = 0; m < 8; ++m) {
            const float vj = __shfl(P0[m], j);
            const float vb0 = __shfl(P0[m], wl);
            const float vb1 = __shfl(P1[m], wl);
            const float vb = slot ? vb1 : vb0;
            if (lane == j) P0[m] = vb;
            if (lane == wl) {
              if (slot) P1[m] = vj;
              else P0[m] = vj;
            }
          }
          if (lane < NT) {           // swap trailing cols in LDS
            const int col0 = c0 + 8 + lane * 4;
            float4 xx = *reinterpret_cast<float4*>(&Al[jc * ALD + col0]);
            float4 yy = *reinterpret_cast<float4*>(&Al[bi * ALD + col0]);
            *reinterpret_cast<float4*>(&Al[jc * ALD + col0]) = yy;
            *reinterpret_cast<float4*>(&Al[bi * ALD + col0]) = xx;
          }
          WFENCE();
        }
        const float rpv = __builtin_amdgcn_rcpf(pv);
        const bool up0 = e0 && (lane > j);
        const float L0 = P0[j] * rpv;
        const float L1 = P1[j] * rpv;
        if (up0) P0[j] = L0;
        if (e1) P1[j] = L1;
#pragma unroll
        for (int jj = j + 1; jj < 8; ++jj) {
          const float u = __shfl(P0[jj], j);
          if (up0) P0[jj] -= L0 * u;
          if (e1) P1[jj] -= L1 * u;
        }
        ls += logf(fabsf(pv));
        if (pv < 0.f) neg ^= 1;
      }
      // write back panel (L and U parts) for solve/trailing waves
      if (e0) {
        float4 x = {P0[0], P0[1], P0[2], P0[3]};
        float4 y = {P0[4], P0[5], P0[6], P0[7]};
        *reinterpret_cast<float4*>(&Al[(c0 + lane) * ALD + c0]) = x;
        *reinterpret_cast<float4*>(&Al[(c0 + lane) * ALD + c0 + 4]) = y;
      }
      if (e1) {
        float4 x = {P1[0], P1[1], P1[2], P1[3]};
        float4 y = {P1[4], P1[5], P1[6], P1[7]};
        *reinterpret_cast<float4*>(&Al[(c0 + 64 + lane) * ALD + c0]) = x;
        *reinterpret_cast<float4*>(&Al[(c0 + 64 + lane) * ALD + c0 + 4]) = y;
      }
    }
    __syncthreads();

    if (NC > 0) {
      // ---- U12 solve: one column per thread ----
      if (tid < NC) {
        const int ca = c0 + 8 + tid;
        float a[8];
#pragma unroll
        for (int i = 0; i < 8; ++i) a[i] = Al[(c0 + i) * ALD + ca];
#pragma unroll
        for (int jj = 1; jj < 8; ++jj)
#pragma unroll
          for (int i = 0; i < jj; ++i) {
            const float Lv = Al[(c0 + jj) * ALD + c0 + i];  // broadcast
            a[jj] -= Lv * a[i];
          }
#pragma unroll
        for (int i = 0; i < 8; ++i) Al[(c0 + i) * ALD + ca] = a[i];
      }
      __syncthreads();

      // ---- trailing rank-8 update: one row per thread ----
      if (tid < NC) {
        const int r = c0 + 8 + tid;
        const float4 lx =
            *reinterpret_cast<const float4*>(&Al[r * ALD + c0]);
        const float4 ly =
            *reinterpret_cast<const float4*>(&Al[r * ALD + c0 + 4]);
        float Lr[8];
        Lr[0] = lx.x; Lr[1] = lx.y; Lr[2] = lx.z; Lr[3] = lx.w;
        Lr[4] = ly.x; Lr[5] = ly.y; Lr[6] = ly.z; Lr[7] = ly.w;
        for (int ct = 0; ct < NT; ++ct) {
          const int col0 = c0 + 8 + ct * 4;
          float4 u[8];
#pragma unroll
          for (int i = 0; i < 8; ++i)
            u[i] =
                *reinterpret_cast<const float4*>(&Al[(c0 + i) * ALD + col0]);
          float4 x = *reinterpret_cast<float4*>(&Al[r * ALD + col0]);
#pragma unroll
          for (int i = 0; i < 8; ++i) {
            x.x -= Lr[i] * u[i].x;
            x.y -= Lr[i] * u[i].y;
            x.z -= Lr[i] * u[i].z;
            x.w -= Lr[i] * u[i].w;
          }
          *reinterpret_cast<float4*>(&Al[r * ALD + col0]) = x;
        }
      }
    }
    __syncthreads();
  }

  if (tid == 0) {
    const float LMIN = -11.5129254f, LMAX = 11.5129254f;  // log(1e-5), log(1e5)
    float c;
    if (neg ^ sgn) c = LMIN;              // det <= 0 -> clipped to 1e-5
    else c = fminf(fmaxf(ls, LMIN), LMAX);
    logdet[f] = c;
  }
}

// ---------------------------------------------------------------------------
// quad body: nt split into 2 groups of 3 -> 24 live acc regs (was 48).
// ---------------------------------------------------------------------------
__device__ __forceinline__ void quad_body(const int tid, const int idx,
                                          const float* __restrict__ z,
                                          const float* __restrict__ W,
                                          float* __restrict__ partial,
                                          float* smem) {
  unsigned short* Zb = reinterpret_cast<unsigned short*>(smem);
  unsigned short* Wb = Zb + 128 * ZLD;

  const int lane = tid & 63, wave = tid >> 6;
  const int n0 = (idx & 31) * 128;
  const int f0 = (idx >> 5) * 16;
  const int lrow = lane & 15;
  const int lq = lane >> 4;
  const int lk8 = lq * 8;
  const int rgrp = tid >> 3;
  const int cgrp = tid & 7;

  float dotacc[2][4];
#pragma unroll
  for (int mt = 0; mt < 2; ++mt)
#pragma unroll
    for (int i = 0; i < 4; ++i) dotacc[mt][i] = 0.f;

  for (int ff = 0; ff < 16; ++ff) {
    const int f = f0 + ff;
#pragma unroll
    for (int p = 0; p < 4; ++p) {
      int r = p * 32 + rgrp;
      const float4* src = reinterpret_cast<const float4*>(
          z + (size_t)(n0 + r) * 24576 + (size_t)f * 96);
#pragma unroll
      for (int cc = 0; cc < 3; ++cc) {
        int c = cgrp + cc * 8;
        float4 d = src[c];
        ushort4 s;
        s.x = f2bf(d.x); s.y = f2bf(d.y); s.z = f2bf(d.z); s.w = f2bf(d.w);
        *reinterpret_cast<ushort4*>(&Zb[r * ZLD + c * 4]) = s;
      }
    }
    const float4* wsrc =
        reinterpret_cast<const float4*>(W + (size_t)f * 9216);
#pragma unroll
    for (int it = 0; it < 9; ++it) {
      int c = tid + it * 256;
      int k = c / 24, q4 = (c % 24) << 2;
      float4 d = wsrc[c];
      ushort4 s;
      s.x = f2bf(d.x); s.y = f2bf(d.y); s.z = f2bf(d.z); s.w = f2bf(d.w);
      *reinterpret_cast<ushort4*>(&Wb[k * ZLD + q4]) = s;
    }
    __syncthreads();

#pragma unroll
    for (int g = 0; g < 2; ++g) {
      f32x4 acc[2][3];
#pragma unroll
      for (int mt = 0; mt < 2; ++mt)
#pragma unroll
        for (int n3 = 0; n3 < 3; ++n3)
          acc[mt][n3] = (f32x4){0.f, 0.f, 0.f, 0.f};

#pragma unroll
      for (int ks = 0; ks < 3; ++ks) {
        bf16x8 a0 = *reinterpret_cast<const bf16x8*>(
            &Zb[(wave * 32 + lrow) * ZLD + ks * 32 + lk8]);
        bf16x8 a1 = *reinterpret_cast<const bf16x8*>(
            &Zb[(wave * 32 + 16 + lrow) * ZLD + ks * 32 + lk8]);
#pragma unroll
        for (int n3 = 0; n3 < 3; ++n3) {
          const int nt = g * 3 + n3;
          bf16x8 b = *reinterpret_cast<const bf16x8*>(
              &Wb[(nt * 16 + lrow) * ZLD + ks * 32 + lk8]);
          acc[0][n3] = __builtin_amdgcn_mfma_f32_16x16x32_bf16(a0, b,
                                                              acc[0][n3],
                                                              0, 0, 0);
          acc[1][n3] = __builtin_amdgcn_mfma_f32_16x16x32_bf16(a1, b,
                                                              acc[1][n3],
                                                              0, 0, 0);
        }
      }

#pragma unroll
      for (int mt = 0; mt < 2; ++mt) {
        int rbase = wave * 32 + mt * 16 + lq * 4;
#pragma unroll
        for (int i = 0; i < 4; ++i) {
          int row = rbase + i;
          float s = 0.f;
#pragma unroll
          for (int n3 = 0; n3 < 3; ++n3) {
            float zv = bf2f(Zb[row * ZLD + (g * 3 + n3) * 16 + lrow]);
            s += acc[mt][n3][i] * zv;
          }
          dotacc[mt][i] += s;
        }
      }
    }
    __syncthreads();
  }

#pragma unroll
  for (int mt = 0; mt < 2; ++mt)
#pragma unroll
    for (int i = 0; i < 4; ++i) {
      float v = dotacc[mt][i];
      v += __shfl_xor(v, 1);
      v += __shfl_xor(v, 2);
      v += __shfl_xor(v, 4);
      v += __shfl_xor(v, 8);
      dotacc[mt][i] = v;
    }
  if (lrow == 0) {
#pragma unroll
    for (int mt = 0; mt < 2; ++mt) {
      int row = wave * 32 + mt * 16 + lq * 4;
      float4 o = {dotacc[mt][0], dotacc[mt][1], dotacc[mt][2], dotacc[mt][3]};
      *reinterpret_cast<float4*>(
          &partial[(size_t)(idx >> 5) * 4096 + n0 + row]) = o;
    }
  }
}

// ---------------------------------------------------------------------------
// Fused kernel: blocks 0..255 det (4 waves), 256..767 quad (8 waves).
// <=128 VGPR (launch_bounds) -> 16 waves/CU -> det+quad co-resident.
// ---------------------------------------------------------------------------
__global__ __launch_bounds__(256, 4) void fused_kernel(
    const float* __restrict__ z, const float* __restrict__ W,
    const float* __restrict__ S1, float* __restrict__ partial,
    float* __restrict__ logdet) {
  __shared__ alignas(16) float smem[11648];   // 46,592 B union
  if (blockIdx.x < 256) {
    det_body(threadIdx.x, blockIdx.x, W, S1, logdet, smem);
  } else {
    quad_body(threadIdx.x, blockIdx.x - 256, z, W, partial, smem);
  }
}

// ---------------------------------------------------------------------------
// finalize: out[n] = sum_ft partial[ft][n] - sum_f logdet[f] + log(n1/n2)
// ---------------------------------------------------------------------------
__global__ __launch_bounds__(256) void finalize_kernel(
    const float* __restrict__ partial, const float* __restrict__ logdet,
    const int* __restrict__ n1p, const int* __restrict__ n2p,
    float* __restrict__ out) {
  __shared__ float red[256];
  const int t = threadIdx.x;
  red[t] = logdet[t];
  __syncthreads();
  for (int s = 128; s > 0; s >>= 1) {
    if (t < s) red[t] += red[t + s];
    __syncthreads();
  }
  const float S = red[0];
  const int n = blockIdx.x * 256 + t;
  float acc = 0.f;
#pragma unroll
  for (int ft = 0; ft < 16; ++ft) acc += partial[ft * 4096 + n];
  const float cst = logf((float)(*n1p) / (float)(*n2p));
  out[n] = acc - S + cst;
}

// ---------------------------------------------------------------------------
extern "C" void kernel_launch(void* const* d_in, const int* in_sizes, int n_in,
                              void* d_out, int out_size, void* d_ws,
                              size_t ws_size, hipStream_t stream) {
  const float* z  = (const float*)d_in[0];
  const float* s1 = (const float*)d_in[1];
  // d_in[2] = sigma_2 (unused by the reference)
  const float* w  = (const float*)d_in[3];
  const int* n1   = (const int*)d_in[4];
  const int* n2   = (const int*)d_in[5];
  float* out      = (float*)d_out;

  char* ws = (char*)d_ws;
  float* partial = (float*)ws;                 // 16*4096*4 = 262,144 B
  float* logdet  = (float*)(ws + 262144);      // 256*4     =   1,024 B

  fused_kernel<<<dim3(768), dim3(256), 0, stream>>>(z, w, s1, partial, logdet);
  finalize_kernel<<<dim3(16), dim3(256), 0, stream>>>(partial, logdet, n1, n2,
                                                      out);
}

// Round 8
// 556.071 us; speedup vs baseline: 1.1776x; 1.1401x over previous
//
#include <hip/hip_runtime.h>

// ---------------------------------------------------------------------------
// out[n] = sum_f ( z_nf^T W_f z_nf - log(clip(det(W_f S1_f + I),1e-5,1e5)) )
//          + log(n1/n2)
// N=4096, K=256, P2=96
//
// R11: quad staging pipelined (T14 async-STAGE split):
//  - prefetch next-ff z tile into 12 float4 regs right after the staging
//    barrier -> HBM latency (~900cy) hides under current tile's MFMA+epilogue
//  - after the compute barrier: issue W(ff+1) loads (L2-hot), then convert+
//    write the prefetched z (covers W latency), then convert+write W
//  - acc regrouped 3 groups x 2 nt (16 live acc regs) to fit zpre(48) under
//    the 128-VGPR cap; a0/a1 re-read per group (+12 ds_read_b128, ~150cy)
//  - det (4-wave) and finalize unchanged from R10.
// ---------------------------------------------------------------------------

typedef __attribute__((ext_vector_type(8))) short bf16x8;
typedef __attribute__((ext_vector_type(4))) float f32x4;

#define WFENCE() asm volatile("" ::: "memory")

__device__ __forceinline__ unsigned short f2bf(float x) {
  unsigned int u = __builtin_bit_cast(unsigned int, x);
  u += 0x7fffu + ((u >> 16) & 1u);   // round-to-nearest-even
  return (unsigned short)(u >> 16);
}
__device__ __forceinline__ float bf2f(unsigned short h) {
  unsigned int u = ((unsigned int)h) << 16;
  return __builtin_bit_cast(float, u);
}

#define ALD 100   // Al row stride (dwords)
#define WLD 35    // Wc row stride
#define ZLD 104

// ---------------------------------------------------------------------------
// det body: 4 waves (unchanged from R10).
// ---------------------------------------------------------------------------
__device__ __forceinline__ void det_body(const int tid, const int f,
                                         const float* __restrict__ W,
                                         const float* __restrict__ S1,
                                         float* __restrict__ logdet,
                                         float* smem) {
  float* Wc = smem;          // 96*35 floats (GEMM phase only)
  float* Sc = smem + 3360;   // 32*100 floats (GEMM phase only)
  float* Al = smem;          // 96*100 floats (after GEMM)

  const int lane = tid & 63;
  const float* Wg = W + (size_t)f * 9216;
  const float* Sg = S1 + (size_t)f * 9216;

  const int i0 = (tid >> 3) * 3;    // 32 row-groups x 3
  const int j0 = (tid & 7) * 12;    // 8 col-groups x 12

  float acc[3][12];
#pragma unroll
  for (int a = 0; a < 3; ++a)
#pragma unroll
    for (int b = 0; b < 12; ++b) acc[a][b] = 0.f;

  for (int kc = 0; kc < 3; ++kc) {
#pragma unroll
    for (int it = 0; it < 3; ++it) {
      int c = tid + it * 256;          // 0..767
      int i = c >> 3;
      int k4 = (c & 7) << 2;
      const float4 v =
          *reinterpret_cast<const float4*>(Wg + i * 96 + kc * 32 + k4);
      Wc[i * WLD + k4 + 0] = v.x;
      Wc[i * WLD + k4 + 1] = v.y;
      Wc[i * WLD + k4 + 2] = v.z;
      Wc[i * WLD + k4 + 3] = v.w;
    }
#pragma unroll
    for (int it = 0; it < 3; ++it) {
      int c = tid + it * 256;
      int kk = c / 24;
      int j4 = (c % 24) << 2;
      const float4 v =
          *reinterpret_cast<const float4*>(Sg + (kc * 32 + kk) * 96 + j4);
      *reinterpret_cast<float4*>(&Sc[kk * 100 + j4]) = v;
    }
    __syncthreads();
#pragma unroll 2
    for (int kk = 0; kk < 32; ++kk) {
      float wv[3];
#pragma unroll
      for (int r = 0; r < 3; ++r) wv[r] = Wc[(i0 + r) * WLD + kk];
      float sv[12];
      const float4 s0 = *reinterpret_cast<const float4*>(&Sc[kk * 100 + j0]);
      const float4 s1 =
          *reinterpret_cast<const float4*>(&Sc[kk * 100 + j0 + 4]);
      const float4 s2 =
          *reinterpret_cast<const float4*>(&Sc[kk * 100 + j0 + 8]);
      sv[0] = s0.x; sv[1] = s0.y; sv[2] = s0.z; sv[3] = s0.w;
      sv[4] = s1.x; sv[5] = s1.y; sv[6] = s1.z; sv[7] = s1.w;
      sv[8] = s2.x; sv[9] = s2.y; sv[10] = s2.z; sv[11] = s2.w;
#pragma unroll
      for (int a = 0; a < 3; ++a)
#pragma unroll
        for (int b = 0; b < 12; ++b) acc[a][b] += wv[a] * sv[b];
    }
    __syncthreads();
  }

  // Al = acc + I (overwrites Wc/Sc; all GEMM reads done by the barrier)
#pragma unroll
  for (int a = 0; a < 3; ++a) {
    int i = i0 + a;
#pragma unroll
    for (int c4 = 0; c4 < 3; ++c4) {
      float4 v;
      v.x = acc[a][c4 * 4 + 0] + ((i == j0 + c4 * 4 + 0) ? 1.f : 0.f);
      v.y = acc[a][c4 * 4 + 1] + ((i == j0 + c4 * 4 + 1) ? 1.f : 0.f);
      v.z = acc[a][c4 * 4 + 2] + ((i == j0 + c4 * 4 + 2) ? 1.f : 0.f);
      v.w = acc[a][c4 * 4 + 3] + ((i == j0 + c4 * 4 + 3) ? 1.f : 0.f);
      *reinterpret_cast<float4*>(&Al[i * ALD + j0 + c4 * 4]) = v;
    }
  }
  __syncthreads();

  // ======================= blocked LU, NB = 8 ==============================
  float ls = 0.f;
  int neg = 0;
  int sgn = 0;

  for (int p = 0; p < 12; ++p) {
    const int c0 = p * 8;
    const int NC = 88 - c0;
    const int NT = NC >> 2;

    if (tid < 64) {
      const bool e0 = lane <= 95 - c0;
      const bool e1 = (c0 < 32) && (lane <= 31 - c0);
      float P0[8], P1[8];
#pragma unroll
      for (int m = 0; m < 8; ++m) { P0[m] = 0.f; P1[m] = 0.f; }
      if (e0) {
        const float4 x =
            *reinterpret_cast<const float4*>(&Al[(c0 + lane) * ALD + c0]);
        const float4 y =
            *reinterpret_cast<const float4*>(&Al[(c0 + lane) * ALD + c0 + 4]);
        P0[0] = x.x; P0[1] = x.y; P0[2] = x.z; P0[3] = x.w;
        P0[4] = y.x; P0[5] = y.y; P0[6] = y.z; P0[7] = y.w;
      }
      if (e1) {
        const float4 x = *reinterpret_cast<const float4*>(
            &Al[(c0 + 64 + lane) * ALD + c0]);
        const float4 y = *reinterpret_cast<const float4*>(
            &Al[(c0 + 64 + lane) * ALD + c0 + 4]);
        P1[0] = x.x; P1[1] = x.y; P1[2] = x.z; P1[3] = x.w;
        P1[4] = y.x; P1[5] = y.y; P1[6] = y.z; P1[7] = y.w;
      }

#pragma unroll
      for (int j = 0; j < 8; ++j) {
        const int jc = c0 + j;
        float pv;
        int tried = 0;
        for (;;) {
          pv = __shfl(P0[j], j);
          if (fabsf(pv) >= 1e-3f || tried) break;
          tried = 1;
          unsigned k0 = (e0 && lane >= j)
                            ? ((__float_as_uint(fabsf(P0[j])) & ~127u) |
                               (unsigned)lane)
                            : 0u;
          unsigned k1 = e1 ? ((__float_as_uint(fabsf(P1[j])) & ~127u) | 64u |
                              (unsigned)lane)
                           : 0u;
          unsigned key = k0 > k1 ? k0 : k1;
#pragma unroll
          for (int m = 1; m < 64; m <<= 1) {
            unsigned o = (unsigned)__shfl_xor((int)key, m);
            key = key > o ? key : o;
          }
          const int wl = (int)(key & 63u);
          const int slot = (int)((key >> 6) & 1u);
          const int bi = c0 + slot * 64 + wl;
          if (bi <= jc) break;
          sgn ^= 1;
#pragma unroll
          for (int m = 0; m < 8; ++m) {
            const float vj = __shfl(P0[m], j);
            const float vb0 = __shfl(P0[m], wl);
            const float vb1 = __shfl(P1[m], wl);
            const float vb = slot ? vb1 : vb0;
            if (lane == j) P0[m] = vb;
            if (lane == wl) {
              if (slot) P1[m] = vj;
              else P0[m] = vj;
            }
          }
          if (lane < NT) {
            const int col0 = c0 + 8 + lane * 4;
            float4 xx = *reinterpret_cast<float4*>(&Al[jc * ALD + col0]);
            float4 yy = *reinterpret_cast<float4*>(&Al[bi * ALD + col0]);
            *reinterpret_cast<float4*>(&Al[jc * ALD + col0]) = yy;
            *reinterpret_cast<float4*>(&Al[bi * ALD + col0]) = xx;
          }
          WFENCE();
        }
        const float rpv = __builtin_amdgcn_rcpf(pv);
        const bool up0 = e0 && (lane > j);
        const float L0 = P0[j] * rpv;
        const float L1 = P1[j] * rpv;
        if (up0) P0[j] = L0;
        if (e1) P1[j] = L1;
#pragma unroll
        for (int jj = j + 1; jj < 8; ++jj) {
          const float u = __shfl(P0[jj], j);
          if (up0) P0[jj] -= L0 * u;
          if (e1) P1[jj] -= L1 * u;
        }
        ls += logf(fabsf(pv));
        if (pv < 0.f) neg ^= 1;
      }
      if (e0) {
        float4 x = {P0[0], P0[1], P0[2], P0[3]};
        float4 y = {P0[4], P0[5], P0[6], P0[7]};
        *reinterpret_cast<float4*>(&Al[(c0 + lane) * ALD + c0]) = x;
        *reinterpret_cast<float4*>(&Al[(c0 + lane) * ALD + c0 + 4]) = y;
      }
      if (e1) {
        float4 x = {P1[0], P1[1], P1[2], P1[3]};
        float4 y = {P1[4], P1[5], P1[6], P1[7]};
        *reinterpret_cast<float4*>(&Al[(c0 + 64 + lane) * ALD + c0]) = x;
        *reinterpret_cast<float4*>(&Al[(c0 + 64 + lane) * ALD + c0 + 4]) = y;
      }
    }
    __syncthreads();

    if (NC > 0) {
      if (tid < NC) {
        const int ca = c0 + 8 + tid;
        float a[8];
#pragma unroll
        for (int i = 0; i < 8; ++i) a[i] = Al[(c0 + i) * ALD + ca];
#pragma unroll
        for (int jj = 1; jj < 8; ++jj)
#pragma unroll
          for (int i = 0; i < jj; ++i) {
            const float Lv = Al[(c0 + jj) * ALD + c0 + i];  // broadcast
            a[jj] -= Lv * a[i];
          }
#pragma unroll
        for (int i = 0; i < 8; ++i) Al[(c0 + i) * ALD + ca] = a[i];
      }
      __syncthreads();

      if (tid < NC) {
        const int r = c0 + 8 + tid;
        const float4 lx =
            *reinterpret_cast<const float4*>(&Al[r * ALD + c0]);
        const float4 ly =
            *reinterpret_cast<const float4*>(&Al[r * ALD + c0 + 4]);
        float Lr[8];
        Lr[0] = lx.x; Lr[1] = lx.y; Lr[2] = lx.z; Lr[3] = lx.w;
        Lr[4] = ly.x; Lr[5] = ly.y; Lr[6] = ly.z; Lr[7] = ly.w;
        for (int ct = 0; ct < NT; ++ct) {
          const int col0 = c0 + 8 + ct * 4;
          float4 u[8];
#pragma unroll
          for (int i = 0; i < 8; ++i)
            u[i] =
                *reinterpret_cast<const float4*>(&Al[(c0 + i) * ALD + col0]);
          float4 x = *reinterpret_cast<float4*>(&Al[r * ALD + col0]);
#pragma unroll
          for (int i = 0; i < 8; ++i) {
            x.x -= Lr[i] * u[i].x;
            x.y -= Lr[i] * u[i].y;
            x.z -= Lr[i] * u[i].z;
            x.w -= Lr[i] * u[i].w;
          }
          *reinterpret_cast<float4*>(&Al[r * ALD + col0]) = x;
        }
      }
    }
    __syncthreads();
  }

  if (tid == 0) {
    const float LMIN = -11.5129254f, LMAX = 11.5129254f;  // log(1e-5), log(1e5)
    float c;
    if (neg ^ sgn) c = LMIN;
    else c = fminf(fmaxf(ls, LMIN), LMAX);
    logdet[f] = c;
  }
}

// ---------------------------------------------------------------------------
// quad body: z prefetched one ff ahead into registers (T14); W staged in the
// write phase with loads issued before z-consumption. 3 groups x 2 nt.
// ---------------------------------------------------------------------------
__device__ __forceinline__ void quad_body(const int tid, const int idx,
                                          const float* __restrict__ z,
                                          const float* __restrict__ W,
                                          float* __restrict__ partial,
                                          float* smem) {
  unsigned short* Zb = reinterpret_cast<unsigned short*>(smem);
  unsigned short* Wb = Zb + 128 * ZLD;

  const int lane = tid & 63, wave = tid >> 6;
  const int n0 = (idx & 31) * 128;
  const int f0 = (idx >> 5) * 16;
  const int lrow = lane & 15;
  const int lq = lane >> 4;
  const int lk8 = lq * 8;
  const int rgrp = tid >> 3;
  const int cgrp = tid & 7;

  float dotacc[2][4];
#pragma unroll
  for (int mt = 0; mt < 2; ++mt)
#pragma unroll
    for (int i = 0; i < 4; ++i) dotacc[mt][i] = 0.f;

  // ---- prologue: stage ff=0 (z + W), barrier ----
  {
    const int f = f0;
#pragma unroll
    for (int p = 0; p < 4; ++p) {
      int r = p * 32 + rgrp;
      const float4* src = reinterpret_cast<const float4*>(
          z + (size_t)(n0 + r) * 24576 + (size_t)f * 96);
#pragma unroll
      for (int cc = 0; cc < 3; ++cc) {
        int c = cgrp + cc * 8;
        float4 d = src[c];
        ushort4 s;
        s.x = f2bf(d.x); s.y = f2bf(d.y); s.z = f2bf(d.z); s.w = f2bf(d.w);
        *reinterpret_cast<ushort4*>(&Zb[r * ZLD + c * 4]) = s;
      }
    }
    const float4* wsrc =
        reinterpret_cast<const float4*>(W + (size_t)f * 9216);
#pragma unroll
    for (int it = 0; it < 9; ++it) {
      int c = tid + it * 256;
      int k = c / 24, q4 = (c % 24) << 2;
      float4 d = wsrc[c];
      ushort4 s;
      s.x = f2bf(d.x); s.y = f2bf(d.y); s.z = f2bf(d.z); s.w = f2bf(d.w);
      *reinterpret_cast<ushort4*>(&Wb[k * ZLD + q4]) = s;
    }
    __syncthreads();
  }

  for (int ff = 0; ff < 16; ++ff) {
    const int fn = f0 + ff + 1;

    // ---- issue next-ff z prefetch (rides under MFMA + epilogue) ----
    float4 zpre[12];
    if (ff < 15) {
#pragma unroll
      for (int p = 0; p < 4; ++p) {
        int r = p * 32 + rgrp;
        const float4* src = reinterpret_cast<const float4*>(
            z + (size_t)(n0 + r) * 24576 + (size_t)fn * 96);
#pragma unroll
        for (int cc = 0; cc < 3; ++cc) zpre[p * 3 + cc] = src[cgrp + cc * 8];
      }
    }

    // ---- compute current ff: 3 groups of 2 nt ----
#pragma unroll
    for (int g = 0; g < 3; ++g) {
      f32x4 acc[2][2];
#pragma unroll
      for (int mt = 0; mt < 2; ++mt)
#pragma unroll
        for (int n2 = 0; n2 < 2; ++n2)
          acc[mt][n2] = (f32x4){0.f, 0.f, 0.f, 0.f};

#pragma unroll
      for (int ks = 0; ks < 3; ++ks) {
        bf16x8 a0 = *reinterpret_cast<const bf16x8*>(
            &Zb[(wave * 32 + lrow) * ZLD + ks * 32 + lk8]);
        bf16x8 a1 = *reinterpret_cast<const bf16x8*>(
            &Zb[(wave * 32 + 16 + lrow) * ZLD + ks * 32 + lk8]);
#pragma unroll
        for (int n2 = 0; n2 < 2; ++n2) {
          const int nt = g * 2 + n2;
          bf16x8 b = *reinterpret_cast<const bf16x8*>(
              &Wb[(nt * 16 + lrow) * ZLD + ks * 32 + lk8]);
          acc[0][n2] = __builtin_amdgcn_mfma_f32_16x16x32_bf16(a0, b,
                                                              acc[0][n2],
                                                              0, 0, 0);
          acc[1][n2] = __builtin_amdgcn_mfma_f32_16x16x32_bf16(a1, b,
                                                              acc[1][n2],
                                                              0, 0, 0);
        }
      }

#pragma unroll
      for (int mt = 0; mt < 2; ++mt) {
        int rbase = wave * 32 + mt * 16 + lq * 4;
#pragma unroll
        for (int i = 0; i < 4; ++i) {
          int row = rbase + i;
          float s = 0.f;
#pragma unroll
          for (int n2 = 0; n2 < 2; ++n2) {
            float zv = bf2f(Zb[row * ZLD + (g * 2 + n2) * 16 + lrow]);
            s += acc[mt][n2][i] * zv;
          }
          dotacc[mt][i] += s;
        }
      }
    }
    __syncthreads();   // all reads of Zb/Wb(ff) complete

    if (ff < 15) {
      // ---- issue W(fn) loads first (L2-hot; latency hides under z writes) --
      const float4* wsrc =
          reinterpret_cast<const float4*>(W + (size_t)fn * 9216);
      float4 wld[9];
#pragma unroll
      for (int it = 0; it < 9; ++it) wld[it] = wsrc[tid + it * 256];

      // ---- convert + write prefetched z ----
#pragma unroll
      for (int p = 0; p < 4; ++p) {
        int r = p * 32 + rgrp;
#pragma unroll
        for (int cc = 0; cc < 3; ++cc) {
          int c = cgrp + cc * 8;
          float4 d = zpre[p * 3 + cc];
          ushort4 s;
          s.x = f2bf(d.x); s.y = f2bf(d.y); s.z = f2bf(d.z); s.w = f2bf(d.w);
          *reinterpret_cast<ushort4*>(&Zb[r * ZLD + c * 4]) = s;
        }
      }
      // ---- convert + write W ----
#pragma unroll
      for (int it = 0; it < 9; ++it) {
        int c = tid + it * 256;
        int k = c / 24, q4 = (c % 24) << 2;
        float4 d = wld[it];
        ushort4 s;
        s.x = f2bf(d.x); s.y = f2bf(d.y); s.z = f2bf(d.z); s.w = f2bf(d.w);
        *reinterpret_cast<ushort4*>(&Wb[k * ZLD + q4]) = s;
      }
      __syncthreads();   // next iteration's reads see the writes
    }
  }

#pragma unroll
  for (int mt = 0; mt < 2; ++mt)
#pragma unroll
    for (int i = 0; i < 4; ++i) {
      float v = dotacc[mt][i];
      v += __shfl_xor(v, 1);
      v += __shfl_xor(v, 2);
      v += __shfl_xor(v, 4);
      v += __shfl_xor(v, 8);
      dotacc[mt][i] = v;
    }
  if (lrow == 0) {
#pragma unroll
    for (int mt = 0; mt < 2; ++mt) {
      int row = wave * 32 + mt * 16 + lq * 4;
      float4 o = {dotacc[mt][0], dotacc[mt][1], dotacc[mt][2], dotacc[mt][3]};
      *reinterpret_cast<float4*>(
          &partial[(size_t)(idx >> 5) * 4096 + n0 + row]) = o;
    }
  }
}

// ---------------------------------------------------------------------------
// Fused kernel: blocks 0..255 det (4 waves), 256..767 quad (8 waves).
// <=128 VGPR (launch_bounds) -> 16 waves/CU -> det+quad co-resident.
// ---------------------------------------------------------------------------
__global__ __launch_bounds__(256, 4) void fused_kernel(
    const float* __restrict__ z, const float* __restrict__ W,
    const float* __restrict__ S1, float* __restrict__ partial,
    float* __restrict__ logdet) {
  __shared__ alignas(16) float smem[11648];   // 46,592 B union
  if (blockIdx.x < 256) {
    det_body(threadIdx.x, blockIdx.x, W, S1, logdet, smem);
  } else {
    quad_body(threadIdx.x, blockIdx.x - 256, z, W, partial, smem);
  }
}

// ---------------------------------------------------------------------------
// finalize: out[n] = sum_ft partial[ft][n] - sum_f logdet[f] + log(n1/n2)
// ---------------------------------------------------------------------------
__global__ __launch_bounds__(256) void finalize_kernel(
    const float* __restrict__ partial, const float* __restrict__ logdet,
    const int* __restrict__ n1p, const int* __restrict__ n2p,
    float* __restrict__ out) {
  __shared__ float red[256];
  const int t = threadIdx.x;
  red[t] = logdet[t];
  __syncthreads();
  for (int s = 128; s > 0; s >>= 1) {
    if (t < s) red[t] += red[t + s];
    __syncthreads();
  }
  const float S = red[0];
  const int n = blockIdx.x * 256 + t;
  float acc = 0.f;
#pragma unroll
  for (int ft = 0; ft < 16; ++ft) acc += partial[ft * 4096 + n];
  const float cst = logf((float)(*n1p) / (float)(*n2p));
  out[n] = acc - S + cst;
}

// ---------------------------------------------------------------------------
extern "C" void kernel_launch(void* const* d_in, const int* in_sizes, int n_in,
                              void* d_out, int out_size, void* d_ws,
                              size_t ws_size, hipStream_t stream) {
  const float* z  = (const float*)d_in[0];
  const float* s1 = (const float*)d_in[1];
  // d_in[2] = sigma_2 (unused by the reference)
  const float* w  = (const float*)d_in[3];
  const int* n1   = (const int*)d_in[4];
  const int* n2   = (const int*)d_in[5];
  float* out      = (float*)d_out;

  char* ws = (char*)d_ws;
  float* partial = (float*)ws;                 // 16*4096*4 = 262,144 B
  float* logdet  = (float*)(ws + 262144);      // 256*4     =   1,024 B

  fused_kernel<<<dim3(768), dim3(256), 0, stream>>>(z, w, s1, partial, logdet);
  finalize_kernel<<<dim3(16), dim3(256), 0, stream>>>(partial, logdet, n1, n2,
                                                      out);
}